// Round 1
// 2546.748 us; speedup vs baseline: 1.3319x; 1.3319x over previous
//
#include <hip/hip_runtime.h>
#include <math.h>

// SPINN forward, fp32 throughout (argmax trajectory sensitivity forbids bf16/f16).
// Restructured to 2 launches/step:
//   A: fused GEMM  [gates (K=1792,N=1024) || lstm5-sub (K=1024,N=2560)]  -- only depends on X
//   B: gates-reduce + LSTM + argmax + (reduce rows only) track-GEMM + node + stack + next-X
// State tc/sptr/blen ping-pongs between launches (B reads *_in, writes *_out) so the
// 4 slice-blocks per row never race on state.

#define B_ 128
#define CAP 42
#define XW 2048   // X row: [buf_h 0:512 | s1_h 512:1024 | s2_h 1024:1536 | th_old 1536:1792 | pad]
#define GSPLIT 14 // gates k-splits, KS=128 (K=1792)
#define LSPLIT 8  // lstm5-sub k-splits, KS=128 (K=1024)

__device__ __forceinline__ float sigm(float x) { return 1.f / (1.f + expf(-x)); }

// ---------------- repack weights ----------------
// W1T[k][n], k in [0,1792): k<1536 -> W_ih[n][k], else W_hh[n][k-1536].       N=1024
// W2T[k][n], k in [0,1024): k<512 -> W_right[n][k] (s1h), else W_left[n][k-512] (s2h). N=2560
// W3T[k][n], k in [0,256):  W_track[n][k].                                    N=2560
__global__ void k_repack(const float* __restrict__ W_ih, const float* __restrict__ W_hh,
                         const float* __restrict__ W_left, const float* __restrict__ W_right,
                         const float* __restrict__ W_track, const float* __restrict__ b_ih,
                         const float* __restrict__ b_hh,
                         float* __restrict__ W1T, float* __restrict__ W2T,
                         float* __restrict__ W3T, float* __restrict__ b1) {
    size_t idx = (size_t)blockIdx.x * 256 + threadIdx.x;
    const size_t n1 = 1792ull * 1024ull;   // 1,835,008
    const size_t n2 = 1024ull * 2560ull;   // 2,621,440
    const size_t n3 = 256ull * 2560ull;    //   655,360
    if (idx < n1) {
        int k = (int)(idx >> 10), n = (int)(idx & 1023);
        W1T[idx] = (k < 1536) ? W_ih[(size_t)n * 1536 + k] : W_hh[(size_t)n * 256 + (k - 1536)];
    } else if (idx < n1 + n2) {
        size_t r = idx - n1;
        int k = (int)(r / 2560), n = (int)(r % 2560);
        W2T[r] = (k < 512) ? W_right[(size_t)n * 512 + k] : W_left[(size_t)n * 512 + (k - 512)];
    } else if (idx < n1 + n2 + n3) {
        size_t r = idx - n1 - n2;
        int k = (int)(r / 2560), n = (int)(r % 2560);
        W3T[r] = W_track[(size_t)n * 256 + k];
    } else if (idx < n1 + n2 + n3 + 1024) {
        int i = (int)(idx - n1 - n2 - n3);
        b1[i] = b_ih[i] + b_hh[i];
    }
}

// ---------------- init state ----------------
__global__ void k_init(const float* __restrict__ buffers, float* __restrict__ stack,
                       float* __restrict__ X, float* __restrict__ tc,
                       int* __restrict__ sptr, int* __restrict__ blen) {
    int b = blockIdx.x, t = threadIdx.x;
    const float* b0 = buffers + (size_t)b * 40 * 1024;      // buffers[b][0]
    const float* btop = b0 + 39 * 1024;                     // buffers[b][39]
    float* stk = stack + (size_t)b * CAP * 1024;
    for (int j = t; j < 1024; j += 256) { stk[j] = b0[j]; stk[1024 + j] = b0[j]; }
    float* Xb = X + (size_t)b * XW;
    for (int j = t; j < 512; j += 256) {
        Xb[j] = btop[j]; Xb[512 + j] = b0[j]; Xb[1024 + j] = b0[j];
    }
    Xb[1536 + t] = 0.f;           // th_old = 0
    tc[b * 256 + t] = 0.f;
    if (t == 0) { sptr[b] = 2; blen[b] = 40; }
}

// ---------------- fused tiled fp32 GEMM (gates || lstm5-sub), k-split partials ----------------
// blocks [0,224):  gates:  ks=bid>>4 (14), n0=(bid&15)*64,  K-chunk=[ks*128,+128), acol=k
// blocks [224,544): lstm5: ks=b2/40 (8),  n0=(b2%40)*64,   K-chunk=[ks*128,+128), acol=512+k
// per block: 128x64 output tile, 256 threads, acc 8x4, KT=32 inner staging.
__global__ __launch_bounds__(256, 3) void k_gemm(const float* __restrict__ X,
                                                 const float* __restrict__ W1T,
                                                 const float* __restrict__ W2T,
                                                 float* __restrict__ gpart,
                                                 float* __restrict__ lpart) {
    __shared__ float As[32][132];
    __shared__ float Ws[32][68];
    const int bid = blockIdx.x;
    const float* WT; float* out; int N, n0, k0, aoff;
    if (bid < 224) {
        int ks = bid >> 4, nb = bid & 15;
        WT = W1T; out = gpart + (size_t)ks * 128 * 1024;
        N = 1024; n0 = nb * 64; k0 = ks * 128; aoff = 0;
    } else {
        int b2 = bid - 224; int ks = b2 / 40, nb = b2 % 40;
        WT = W2T; out = lpart + (size_t)ks * 128 * 2560;
        N = 2560; n0 = nb * 64; k0 = ks * 128; aoff = 512;
    }
    const int tid = threadIdx.x;
    const int tm = tid >> 4;      // 0..15
    const int tn = tid & 15;      // 0..15

    float acc[8][4];
#pragma unroll
    for (int i = 0; i < 8; i++)
#pragma unroll
        for (int j = 0; j < 4; j++) acc[i][j] = 0.f;

    for (int ki = 0; ki < 128; ki += 32) {
        const int kb = k0 + ki;
        __syncthreads();
        {   // stage A: As[kk][m] = X[m][aoff+kb+kk] ; 2 threads per row, 16 floats each
            int m = tid >> 1;
            int c8 = (tid & 1) * 16;
            const float4* src = (const float4*)(X + (size_t)m * XW + aoff + kb + c8);
#pragma unroll
            for (int j = 0; j < 4; j++) {
                float4 v = src[j];
                int kk = c8 + j * 4;
                As[kk + 0][m] = v.x; As[kk + 1][m] = v.y; As[kk + 2][m] = v.z; As[kk + 3][m] = v.w;
            }
        }
        {   // stage W: Ws[kk][c..c+7] = WT[kb+kk][n0+c..] ; 8 threads per k-row, 8 floats each
            int kk = tid >> 3;
            int c = (tid & 7) * 8;
            const float4* src = (const float4*)(WT + (size_t)(kb + kk) * N + n0 + c);
            float4* dst = (float4*)(&Ws[kk][c]);
            dst[0] = src[0]; dst[1] = src[1];
        }
        __syncthreads();
#pragma unroll 4
        for (int kk = 0; kk < 32; kk++) {
            float a[8], w[4];
            *(float4*)&a[0] = *(const float4*)&As[kk][tm * 4];
            *(float4*)&a[4] = *(const float4*)&As[kk][64 + tm * 4];
            *(float4*)&w[0] = *(const float4*)&Ws[kk][tn * 4];
#pragma unroll
            for (int i = 0; i < 8; i++)
#pragma unroll
                for (int j = 0; j < 4; j++) acc[i][j] += a[i] * w[j];
        }
    }
    float* base = out + n0 + tn * 4;
#pragma unroll
    for (int i = 0; i < 8; i++) {
        int m = (i < 4) ? (tm * 4 + i) : (64 + tm * 4 + (i - 4));
        *(float4*)(base + (size_t)m * N) = make_float4(acc[i][0], acc[i][1], acc[i][2], acc[i][3]);
    }
}

// ---------------- B: LSTM cell + argmax + track-GEMM + node + stack + next-X ----------------
// grid 512 = 128 rows x 4 j-slices (q). All 4 q-blocks of a row redundantly compute the
// LSTM/logits/argmax (deterministic, identical); reduce-node/track/copies are sliced by q.
__global__ __launch_bounds__(256) void k_B(const float* __restrict__ gpart,
                                           const float* __restrict__ lpart,
                                           const float* __restrict__ b1,
                                           const float* __restrict__ b_left,
                                           const float* __restrict__ W3T,
                                           const float* __restrict__ W_trans,
                                           const float* __restrict__ b_trans,
                                           const float* __restrict__ buffers,
                                           float* __restrict__ stack,
                                           float* __restrict__ X,
                                           const float* __restrict__ tc_in,
                                           float* __restrict__ tc_out,
                                           const int* __restrict__ sp_in,
                                           int* __restrict__ sp_out,
                                           const int* __restrict__ bl_in,
                                           int* __restrict__ bl_out,
                                           float* __restrict__ out_s) {
    const int bid = blockIdx.x;
    const int b = bid >> 2, q = bid & 3;
    const int t = threadIdx.x;
    const int sp = sp_in[b], bl = bl_in[b];

    // 1) gather gates partials + LSTM cell
    const float* gp = gpart + (size_t)b * 1024;
    float gi = b1[t], gf = b1[256 + t], gg = b1[512 + t], go = b1[768 + t];
#pragma unroll
    for (int kc = 0; kc < GSPLIT; kc++) {
        const float* p = gp + (size_t)kc * 128 * 1024;
        gi += p[t]; gf += p[256 + t]; gg += p[512 + t]; go += p[768 + t];
    }
    float tcv = tc_in[b * 256 + t];
    float tcn = sigm(gf) * tcv + sigm(gi) * tanhf(gg);
    float thn = sigm(go) * tanhf(tcn);

    __shared__ float sh_th[256];
    __shared__ float red[256][4];
    sh_th[t] = thn;
    red[t][0] = thn * W_trans[t];
    red[t][1] = thn * W_trans[256 + t];
    red[t][2] = thn * W_trans[512 + t];
    red[t][3] = thn * W_trans[768 + t];
    __syncthreads();
    for (int off = 128; off > 0; off >>= 1) {
        if (t < off) {
            red[t][0] += red[t + off][0]; red[t][1] += red[t + off][1];
            red[t][2] += red[t + off][2]; red[t][3] += red[t + off][3];
        }
        __syncthreads();
    }
    // 2) logits + first-max argmax (all threads identically)
    float lg[4]; int tr = 0; float best = -1e30f;
#pragma unroll
    for (int l = 0; l < 4; l++) {
        lg[l] = red[0][l] + b_trans[l];
        if (lg[l] > best) { best = lg[l]; tr = l; }
    }
    if (q == 0 && t == 0) {
#pragma unroll
        for (int l = 0; l < 4; l++) out_s[b * 4 + l] = lg[l];
    }
    const bool do_shift = (tr == 3) && (bl > 2);
    const bool do_red   = (tr == 2) && (sp > 3);
    const int spn = sp + (do_shift ? 1 : 0) - (do_red ? 1 : 0);
    const int bln = bl - (do_shift ? 1 : 0);
    float* stk = stack + (size_t)b * CAP * 1024;

    // 3) reduce rows: lstm5 = sub-partials + b_left + W_track@th_new ; node ; stack[sp-2]=node
    float node_h = 0.f;
    if (do_red && t < 128) {
        const int j = q * 128 + t;
        const float* lp = lpart + (size_t)b * 2560;
        float a  = b_left[j],        ii = b_left[512 + j], f1 = b_left[1024 + j],
              f2 = b_left[1536 + j], oo = b_left[2048 + j];
#pragma unroll
        for (int kc = 0; kc < LSPLIT; kc++) {
            const float* p = lp + (size_t)kc * 128 * 2560;
            a += p[j]; ii += p[512 + j]; f1 += p[1024 + j]; f2 += p[1536 + j]; oo += p[2048 + j];
        }
        const float* w = W3T + j;
#pragma unroll 4
        for (int k = 0; k < 256; k++) {
            float th = sh_th[k];
            const float* wk = w + (size_t)k * 2560;
            a += th * wk[0]; ii += th * wk[512]; f1 += th * wk[1024];
            f2 += th * wk[1536]; oo += th * wk[2048];
        }
        float s1c = stk[(size_t)(sp - 1) * 1024 + 512 + j];
        float s2c = stk[(size_t)(sp - 2) * 1024 + 512 + j];
        float c = tanhf(a) * sigm(ii) + sigm(f1) * s2c + sigm(f2) * s1c;
        float h = sigm(oo) * tanhf(c);
        stk[(size_t)(sp - 2) * 1024 + j] = h;          // own-slice addresses only
        stk[(size_t)(sp - 2) * 1024 + 512 + j] = c;
        node_h = h;
    }
    // 4) shift: push buf_top (sliced 256 floats per q-block; slot sp untouched by any read)
    if (do_shift) {
        const float* bt = buffers + ((size_t)b * 40 + (bl - 1)) * 1024;
        const int idx = q * 256 + t;
        stk[(size_t)sp * 1024 + idx] = bt[idx];
    }
    // 5) build next X (slice j = q*128 + t, t<128)
    float* Xb = X + (size_t)b * XW;
    if (t < 128) {
        const int j = q * 128 + t;
        const float* btn = buffers + ((size_t)b * 40 + (bln - 1)) * 1024;
        Xb[j] = btn[j];                                 // buf_top' h
        float s1h;
        if (do_red)        s1h = node_h;                // just-built node (register)
        else if (do_shift) s1h = buffers[((size_t)b * 40 + (bl - 1)) * 1024 + j];
        else               s1h = stk[(size_t)(sp - 1) * 1024 + j];
        Xb[512 + j] = s1h;
        Xb[1024 + j] = stk[(size_t)(spn - 2) * 1024 + j];  // untouched slot in all 3 cases
    }
    if ((t >> 6) == q) {                                // th_old<-th_new, tc, sliced by q
        Xb[1536 + t] = thn;
        tc_out[b * 256 + t] = tcn;
    }
    if (q == 0 && t == 0) { sp_out[b] = spn; bl_out[b] = bln; }
}

// ---------------- host ----------------
extern "C" void kernel_launch(void* const* d_in, const int* in_sizes, int n_in,
                              void* d_out, int out_size, void* d_ws, size_t ws_size,
                              hipStream_t stream) {
    const float* buffers = (const float*)d_in[0];
    const float* W_left  = (const float*)d_in[1];
    const float* b_left  = (const float*)d_in[2];
    const float* W_right = (const float*)d_in[3];
    const float* W_track = (const float*)d_in[4];
    const float* W_ih    = (const float*)d_in[5];
    const float* W_hh    = (const float*)d_in[6];
    const float* b_ih    = (const float*)d_in[7];
    const float* b_hh    = (const float*)d_in[8];
    const float* W_trans = (const float*)d_in[9];
    const float* b_trans = (const float*)d_in[10];
    float* out = (float*)d_out;

    float* ws = (float*)d_ws;
    size_t off = 0;
    float* W1T   = ws + off; off += 1792ull * 1024;            // 1,835,008
    float* W2T   = ws + off; off += 1024ull * 2560;            // 2,621,440
    float* W3T   = ws + off; off += 256ull * 2560;             //   655,360
    float* b1    = ws + off; off += 1024;
    float* X     = ws + off; off += (size_t)B_ * XW;           //   262,144
    float* tc_a  = ws + off; off += (size_t)B_ * 256;
    float* tc_b  = ws + off; off += (size_t)B_ * 256;
    float* gpart = ws + off; off += (size_t)GSPLIT * B_ * 1024; // 1,835,008
    float* lpart = ws + off; off += (size_t)LSPLIT * B_ * 2560; // 2,621,440
    float* stack = ws + off; off += (size_t)B_ * CAP * 1024;    // 5,505,024
    int* sp_a = (int*)(ws + off); off += 128;
    int* sp_b = (int*)(ws + off); off += 128;
    int* bl_a = (int*)(ws + off); off += 128;
    int* bl_b = (int*)(ws + off); off += 128;

    // one-time (per launch) weight repack + state init
    {
        size_t total = 1792ull * 1024 + 1024ull * 2560 + 256ull * 2560 + 1024;
        int blocks = (int)((total + 255) / 256);
        k_repack<<<blocks, 256, 0, stream>>>(W_ih, W_hh, W_left, W_right, W_track, b_ih, b_hh,
                                             W1T, W2T, W3T, b1);
        k_init<<<B_, 256, 0, stream>>>(buffers, stack, X, tc_a, sp_a, bl_a);
    }

    for (int s = 0; s < 64; s++) {
        k_gemm<<<544, 256, 0, stream>>>(X, W1T, W2T, gpart, lpart);
        const float* tci = (s & 1) ? tc_b : tc_a;  float* tco = (s & 1) ? tc_a : tc_b;
        const int*   spi = (s & 1) ? sp_b : sp_a;  int*   spo = (s & 1) ? sp_a : sp_b;
        const int*   bli = (s & 1) ? bl_b : bl_a;  int*   blo = (s & 1) ? bl_a : bl_b;
        k_B<<<512, 256, 0, stream>>>(gpart, lpart, b1, b_left, W3T, W_trans, b_trans,
                                     buffers, stack, X, tci, tco, spi, spo, bli, blo,
                                     out + (size_t)s * B_ * 4);
    }
    (void)in_sizes; (void)n_in; (void)out_size; (void)ws_size;
}